// Round 5
// baseline (88.181 us; speedup 1.0000x reference)
//
#include <hip/hip_runtime.h>
#include <hip/hip_bf16.h>

typedef float f32x4 __attribute__((ext_vector_type(4)));
typedef float f32x16 __attribute__((ext_vector_type(16)));
typedef __bf16 bf16x8 __attribute__((ext_vector_type(8)));

#define MFMA16(a, b, c) __builtin_amdgcn_mfma_f32_16x16x32_bf16((a), (b), (c), 0, 0, 0)
#define MFMA32(a, b, c) __builtin_amdgcn_mfma_f32_32x32x16_bf16((a), (b), (c), 0, 0, 0)

static __device__ __forceinline__ short f2s(float f) {
    __hip_bfloat16 h = __float2bfloat16(f);
    return *reinterpret_cast<short*>(&h);
}
static __device__ __forceinline__ unsigned int cvtpk(float lo, float hi) {
    unsigned int r;
    asm("v_cvt_pk_bf16_f32 %0, %1, %2" : "=v"(r) : "v"(lo), "v"(hi));
    return r;
}
static __device__ __forceinline__ float exp2f_fast(float x) {
#if __has_builtin(__builtin_amdgcn_exp2f)
    return __builtin_amdgcn_exp2f(x);
#else
    return exp2f(x);
#endif
}

// ---------------------------------------------------------------------------
// Kernel 0: pack adj int32 -> uint8  (values 0..4)   [round-3 verified]
// ---------------------------------------------------------------------------
__global__ __launch_bounds__(256)
void adj_pack(const int* __restrict__ adj, unsigned char* __restrict__ out)
{
    const int i = blockIdx.x * 256 + threadIdx.x;   // handles 16 ints
    const int4* src = reinterpret_cast<const int4*>(adj) + i * 4;
    int4 a = src[0], b = src[1], c = src[2], d = src[3];
    uint4 o;
    o.x = (unsigned)a.x | ((unsigned)a.y << 8) | ((unsigned)a.z << 16) | ((unsigned)a.w << 24);
    o.y = (unsigned)b.x | ((unsigned)b.y << 8) | ((unsigned)b.z << 16) | ((unsigned)b.w << 24);
    o.z = (unsigned)c.x | ((unsigned)c.y << 8) | ((unsigned)c.z << 16) | ((unsigned)c.w << 24);
    o.w = (unsigned)d.x | ((unsigned)d.y << 8) | ((unsigned)d.z << 16) | ((unsigned)d.w << 24);
    reinterpret_cast<uint4*>(out)[i] = o;
}

// ---------------------------------------------------------------------------
// Kernel 1: QKV projection (unchanged, verified).
// ---------------------------------------------------------------------------
__global__ __launch_bounds__(256)
void qkv_gemm(const float* __restrict__ x,
              const float* __restrict__ Wq, const float* __restrict__ bq,
              const float* __restrict__ Wk, const float* __restrict__ bk,
              const float* __restrict__ Wv, const float* __restrict__ bv,
              short* __restrict__ Qb, short* __restrict__ Kb, short* __restrict__ Vb)
{
    __shared__ short As[128 * 72];
    __shared__ short Bs[64 * 72];

    const int tid = threadIdx.x;
    const int lane = tid & 63;
    const int wid = tid >> 6;
    const int wr = wid >> 1, wc = wid & 1;
    const int g = lane >> 4, li = lane & 15;

    const int m0 = blockIdx.x * 128;
    const int gc0 = blockIdx.y * 64;
    const int mat = gc0 >> 8;
    const float* W    = (mat == 0) ? Wq : (mat == 1) ? Wk : Wv;
    const float* bias = (mat == 0) ? bq : (mat == 1) ? bk : bv;
    short* Out        = (mat == 0) ? Qb : (mat == 1) ? Kb : Vb;
    const int wc0 = gc0 & 255;

    f32x4 acc[4][2] = {};

    const int sr = tid >> 4;
    const int sc4 = (tid & 15) * 4;

    for (int k0 = 0; k0 < 256; k0 += 64) {
        __syncthreads();
#pragma unroll
        for (int it = 0; it < 8; ++it) {
            int row = sr + it * 16;
            float4 v = *reinterpret_cast<const float4*>(&x[(m0 + row) * 256 + k0 + sc4]);
            short4 s4;
            s4.x = f2s(v.x); s4.y = f2s(v.y); s4.z = f2s(v.z); s4.w = f2s(v.w);
            *reinterpret_cast<short4*>(&As[row * 72 + sc4]) = s4;
        }
#pragma unroll
        for (int it = 0; it < 4; ++it) {
            int row = sr + it * 16;
            float4 v = *reinterpret_cast<const float4*>(&W[(wc0 + row) * 256 + k0 + sc4]);
            short4 s4;
            s4.x = f2s(v.x); s4.y = f2s(v.y); s4.z = f2s(v.z); s4.w = f2s(v.w);
            *reinterpret_cast<short4*>(&Bs[row * 72 + sc4]) = s4;
        }
        __syncthreads();
#pragma unroll
        for (int ks = 0; ks < 2; ++ks) {
            const int kb = ks * 32 + g * 8;
            bf16x8 a[4], bfr[2];
#pragma unroll
            for (int i = 0; i < 4; ++i)
                a[i] = *reinterpret_cast<const bf16x8*>(&As[(wr * 64 + i * 16 + li) * 72 + kb]);
#pragma unroll
            for (int j = 0; j < 2; ++j)
                bfr[j] = *reinterpret_cast<const bf16x8*>(&Bs[(wc * 32 + j * 16 + li) * 72 + kb]);
#pragma unroll
            for (int i = 0; i < 4; ++i)
#pragma unroll
                for (int j = 0; j < 2; ++j)
                    acc[i][j] = MFMA16(a[i], bfr[j], acc[i][j]);
        }
    }

#pragma unroll
    for (int j = 0; j < 2; ++j) {
        const int colW = wc0 + wc * 32 + j * 16 + li;
        const int h = colW >> 5, d = colW & 31;
        const float bv_ = bias[colW];
#pragma unroll
        for (int i = 0; i < 4; ++i) {
#pragma unroll
            for (int r = 0; r < 4; ++r) {
                const int row = m0 + wr * 64 + i * 16 + g * 4 + r;
                const int bb = row >> 10, nq = row & 1023;
                Out[((bb * 8 + h) * 1024 + nq) * 32 + d] = f2s(acc[i][j][r] + bv_);
            }
        }
    }
}

// ---------------------------------------------------------------------------
// Kernel 2: edge-biased flash attention.
// Grid (32, 64), block 256 = 4 waves.  4-way split-k: wave w owns k-chunk
// [w*256, w*256+256) as 4 tiles of 64.  Per-wave single-buffer V^T in LDS.
// exp2-domain softmax; bias via u8 codes + fp32 ternary select (round-3
// verified primitives).  4-way flash merge in per-wave LDS regions.
// ---------------------------------------------------------------------------
__global__ __launch_bounds__(256)
void attn3(const short* __restrict__ Qb, const short* __restrict__ Kb,
           const short* __restrict__ Vb, const unsigned char* __restrict__ adj8,
           const float* __restrict__ edge_emb, short* __restrict__ AO)
{
    __shared__ __align__(16) short Vsh[4 * 2304];   // 18432 B: per-wave [32 d][72] V^T

    const int tid = threadIdx.x, lane = tid & 63, wid = tid >> 6;
    const int l5 = lane & 31, h32 = lane >> 5;
    const int bh = blockIdx.y, b = bh >> 3, h = bh & 7;
    const int q = blockIdx.x * 32 + l5;

    const short* Qh = Qb + bh * (1024 * 32);
    const short* Kh = Kb + bh * (1024 * 32);
    const short* Vh = Vb + bh * (1024 * 32);
    const unsigned char* adjq = adj8 + (size_t)b * (1024 * 1024) + (size_t)q * 1024;

    // Q fragments (B-operand): col=q=l5, k(d) = c*16 + h32*8 + j
    const bf16x8 qf0 = *reinterpret_cast<const bf16x8*>(&Qh[q * 32 + h32 * 8]);
    const bf16x8 qf1 = *reinterpret_cast<const bf16x8*>(&Qh[q * 32 + 16 + h32 * 8]);

    const float L2E = 1.4426950408889634f;
    float wb[5];
#pragma unroll
    for (int i = 0; i < 5; ++i) wb[i] = edge_emb[i * 8 + h] * L2E;   // fp32 exact

    const float c1 = 0.25503486f;   // log2(e)/sqrt(32)
    const f32x16 zero16 = {};

    f32x16 o = {};
    float m2 = -1e30f, l_run = 0.f;

    short* Vt = &Vsh[wid * 2304];
    const int T0 = wid * 4;

    for (int t = 0; t < 4; ++t) {
        const int k0 = (T0 + t) * 64;

        // ---- stage V^T tile (single buffer; same-wave write->read ordered
        //      by compiler-inserted lgkmcnt waits) ----
        {
            const int kr = k0 + lane;
            int4 v0 = *reinterpret_cast<const int4*>(&Vh[kr * 32 + 0]);
            int4 v1 = *reinterpret_cast<const int4*>(&Vh[kr * 32 + 8]);
            int4 v2 = *reinterpret_cast<const int4*>(&Vh[kr * 32 + 16]);
            int4 v3 = *reinterpret_cast<const int4*>(&Vh[kr * 32 + 24]);
            const short* s0 = reinterpret_cast<const short*>(&v0);
            const short* s1 = reinterpret_cast<const short*>(&v1);
            const short* s2 = reinterpret_cast<const short*>(&v2);
            const short* s3 = reinterpret_cast<const short*>(&v3);
#pragma unroll
            for (int i = 0; i < 8; ++i) {
                Vt[(i) * 72 + lane]      = s0[i];
                Vt[(8 + i) * 72 + lane]  = s1[i];
                Vt[(16 + i) * 72 + lane] = s2[i];
                Vt[(24 + i) * 72 + lane] = s3[i];
            }
        }

        // ---- adj byte loads (4 codes per u32), issued early ----
        unsigned int a4[8];
#pragma unroll
        for (int ks = 0; ks < 2; ++ks)
#pragma unroll
            for (int rg = 0; rg < 4; ++rg)
                a4[ks * 4 + rg] = *reinterpret_cast<const unsigned int*>(
                    &adjq[k0 + ks * 32 + rg * 8 + h32 * 4]);

        // ---- QK^T swapped: S^T[k][q], k-local = (r&3)+8*(r>>2)+4*h32 ----
        f32x16 s[2];
#pragma unroll
        for (int ks = 0; ks < 2; ++ks) {
            const int krow = k0 + ks * 32 + l5;
            bf16x8 kfa = *reinterpret_cast<const bf16x8*>(&Kh[krow * 32 + h32 * 8]);
            bf16x8 kfb = *reinterpret_cast<const bf16x8*>(&Kh[krow * 32 + 16 + h32 * 8]);
            s[ks] = MFMA32(kfa, qf0, zero16);
            s[ks] = MFMA32(kfb, qf1, s[ks]);
        }

        // ---- tile max over raw scores (bias excluded; exp arg stays bounded) ----
        float tm = s[0][0];
#pragma unroll
        for (int ks = 0; ks < 2; ++ks)
#pragma unroll
            for (int r = 0; r < 16; ++r) tm = fmaxf(tm, s[ks][r]);
        tm = fmaxf(tm, __shfl_xor(tm, 32));

        const float m2n = fmaxf(m2, tm * c1);
        const float resc = exp2f_fast(m2 - m2n);
        m2 = m2n;

        float wm[5];
#pragma unroll
        for (int i = 0; i < 5; ++i) wm[i] = wb[i] - m2;

        // ---- p = exp2(s*c1 + wm[adj]); pack bf16 pairs ----
        unsigned int pw[2][8];
        float lsum = 0.f;
#pragma unroll
        for (int ks = 0; ks < 2; ++ks) {
#pragma unroll
            for (int rg = 0; rg < 4; ++rg) {
                const unsigned int aw = a4[ks * 4 + rg];
                float pv[4];
#pragma unroll
                for (int j = 0; j < 4; ++j) {
                    const unsigned int a = (aw >> (j * 8)) & 0xFF;
                    const float base = (a == 0) ? wm[0] : (a == 1) ? wm[1] :
                                       (a == 2) ? wm[2] : (a == 3) ? wm[3] : wm[4];
                    const float pp = exp2f_fast(fmaf(s[ks][rg * 4 + j], c1, base));
                    pv[j] = pp;
                    lsum += pp;
                }
                pw[ks][rg * 2 + 0] = cvtpk(pv[0], pv[1]);
                pw[ks][rg * 2 + 1] = cvtpk(pv[2], pv[3]);
            }
        }
        lsum += __shfl_xor(lsum, 32);
        l_run = l_run * resc + lsum;

        // ---- rescale O (per-lane uniform) ----
#pragma unroll
        for (int r = 0; r < 16; ++r) o[r] *= resc;

        // ---- PV: O^T += V^T . P^T ----
#pragma unroll
        for (int kc = 0; kc < 4; ++kc) {
            const int ks = kc >> 1, half = kc & 1;
            const unsigned int A0 = pw[ks][4 * half + 0], A1 = pw[ks][4 * half + 1];
            const unsigned int B0 = pw[ks][4 * half + 2], B1 = pw[ks][4 * half + 3];
            const unsigned int send0 = h32 ? A0 : B0, send1 = h32 ? A1 : B1;
            const unsigned int rv0 = __shfl_xor(send0, 32);
            const unsigned int rv1 = __shfl_xor(send1, 32);
            const unsigned int own0 = h32 ? B0 : A0, own1 = h32 ? B1 : A1;
            union { unsigned int u[4]; bf16x8 v; } P;
            P.u[0] = h32 ? rv0 : own0;
            P.u[1] = h32 ? rv1 : own1;
            P.u[2] = h32 ? own0 : rv0;
            P.u[3] = h32 ? own1 : rv1;
            bf16x8 vf = *reinterpret_cast<const bf16x8*>(
                &Vt[l5 * 72 + kc * 16 + h32 * 8]);
            o = MFMA32(vf, P.v, o);
        }
    }

    // ---- 4-way split-k flash merge: each wave's scratch = its OWN V region
    //      (1152 floats = 64 lanes x 18 floats: [m2, l, o[16]]) ----
    float* sc = reinterpret_cast<float*>(Vsh);
    {
        float* myb = sc + wid * 1152 + lane * 18;
        myb[0] = m2;
        myb[1] = l_run;
#pragma unroll
        for (int r = 0; r < 16; ++r) myb[2 + r] = o[r];
    }
    __syncthreads();

    if (wid == 0) {
        float mM = -1e30f;
#pragma unroll
        for (int w = 0; w < 4; ++w) mM = fmaxf(mM, sc[w * 1152 + lane * 18]);
        float lM = 0.f;
        f32x16 ov = {};
#pragma unroll
        for (int w = 0; w < 4; ++w) {
            const float* pb = sc + w * 1152 + lane * 18;
            const float aw = exp2f_fast(pb[0] - mM);
            lM += pb[1] * aw;
#pragma unroll
            for (int r = 0; r < 16; ++r) ov[r] += pb[2 + r] * aw;
        }
        const float inv = 1.0f / lM;
        short* dst = &AO[((size_t)(b * 1024 + q)) * 256 + h * 32];
#pragma unroll
        for (int rg = 0; rg < 4; ++rg) {
            short4 s4;
            s4.x = f2s(ov[rg * 4 + 0] * inv);
            s4.y = f2s(ov[rg * 4 + 1] * inv);
            s4.z = f2s(ov[rg * 4 + 2] * inv);
            s4.w = f2s(ov[rg * 4 + 3] * inv);
            *reinterpret_cast<short4*>(&dst[rg * 8 + h32 * 4]) = s4;
        }
    }
}

// ---------------------------------------------------------------------------
// Kernel 3: output projection (unchanged, verified).
// ---------------------------------------------------------------------------
__global__ __launch_bounds__(256)
void out_gemm(const short* __restrict__ AO, const float* __restrict__ Wo,
              const float* __restrict__ bo, float* __restrict__ out)
{
    __shared__ short As[128 * 72];
    __shared__ short Bs[64 * 72];

    const int tid = threadIdx.x, lane = tid & 63, wid = tid >> 6;
    const int wr = wid >> 1, wcn = wid & 1;
    const int g = lane >> 4, li = lane & 15;
    const int m0 = blockIdx.x * 128, n0 = blockIdx.y * 64;

    f32x4 acc[4][2] = {};
    const int ar = tid >> 3, ac8 = (tid & 7) * 8;
    const int br = tid >> 4, bc4 = (tid & 15) * 4;

    for (int k0 = 0; k0 < 256; k0 += 64) {
        __syncthreads();
#pragma unroll
        for (int it = 0; it < 4; ++it) {
            int row = ar + it * 32;
            *reinterpret_cast<int4*>(&As[row * 72 + ac8]) =
                *reinterpret_cast<const int4*>(&AO[(m0 + row) * 256 + k0 + ac8]);
        }
#pragma unroll
        for (int it = 0; it < 4; ++it) {
            int row = br + it * 16;
            float4 v = *reinterpret_cast<const float4*>(&Wo[(n0 + row) * 256 + k0 + bc4]);
            short4 s4; s4.x = f2s(v.x); s4.y = f2s(v.y); s4.z = f2s(v.z); s4.w = f2s(v.w);
            *reinterpret_cast<short4*>(&Bs[row * 72 + bc4]) = s4;
        }
        __syncthreads();
#pragma unroll
        for (int ks = 0; ks < 2; ++ks) {
            const int kb = ks * 32 + g * 8;
            bf16x8 a[4], bb[2];
#pragma unroll
            for (int i = 0; i < 4; ++i)
                a[i] = *reinterpret_cast<const bf16x8*>(&As[(wr * 64 + i * 16 + li) * 72 + kb]);
#pragma unroll
            for (int j = 0; j < 2; ++j)
                bb[j] = *reinterpret_cast<const bf16x8*>(&Bs[(wcn * 32 + j * 16 + li) * 72 + kb]);
#pragma unroll
            for (int i = 0; i < 4; ++i)
#pragma unroll
                for (int j = 0; j < 2; ++j)
                    acc[i][j] = MFMA16(a[i], bb[j], acc[i][j]);
        }
    }
#pragma unroll
    for (int j = 0; j < 2; ++j) {
        const int col = n0 + wcn * 32 + j * 16 + li;
        const float bv_ = bo[col];
#pragma unroll
        for (int i = 0; i < 4; ++i)
#pragma unroll
            for (int r = 0; r < 4; ++r) {
                const int row = m0 + wr * 64 + i * 16 + g * 4 + r;
                out[row * 256 + col] = acc[i][j][r] + bv_;
            }
    }
}

extern "C" void kernel_launch(void* const* d_in, const int* in_sizes, int n_in,
                              void* d_out, int out_size, void* d_ws, size_t ws_size,
                              hipStream_t stream)
{
    const float* x  = (const float*)d_in[0];
    const int*   adj = (const int*)d_in[1];
    const float* Wq = (const float*)d_in[2];
    const float* bq = (const float*)d_in[3];
    const float* Wk = (const float*)d_in[4];
    const float* bk = (const float*)d_in[5];
    const float* Wv = (const float*)d_in[6];
    const float* bv = (const float*)d_in[7];
    const float* Wo = (const float*)d_in[8];
    const float* bo = (const float*)d_in[9];
    const float* ee = (const float*)d_in[10];
    float* out = (float*)d_out;

    // Workspace: Qb/Kb/Vb [64][1024][32] bf16 (4MB each), AO [8192][256] bf16 (4MB),
    // adj8 [8][1024][1024] u8 (8MB)  -> 24MB total
    short* Qb = (short*)d_ws;
    short* Kb = Qb + 2 * 1024 * 1024;
    short* Vb = Kb + 2 * 1024 * 1024;
    short* AO = Vb + 2 * 1024 * 1024;
    unsigned char* adj8 = (unsigned char*)(AO + 2 * 1024 * 1024);

    adj_pack<<<2048, 256, 0, stream>>>(adj, adj8);
    qkv_gemm<<<dim3(64, 12), 256, 0, stream>>>(x, Wq, bq, Wk, bk, Wv, bv, Qb, Kb, Vb);
    attn3<<<dim3(32, 64), 256, 0, stream>>>(Qb, Kb, Vb, adj8, ee, AO);
    out_gemm<<<dim3(64, 4), 256, 0, stream>>>(AO, Wo, bo, out);
}

// Round 7
// 88.106 us; speedup vs baseline: 1.0008x; 1.0008x over previous
//
#include <hip/hip_runtime.h>
#include <hip/hip_bf16.h>

typedef float f32x4 __attribute__((ext_vector_type(4)));
typedef float f32x16 __attribute__((ext_vector_type(16)));
typedef __bf16 bf16x8 __attribute__((ext_vector_type(8)));

#define MFMA16(a, b, c) __builtin_amdgcn_mfma_f32_16x16x32_bf16((a), (b), (c), 0, 0, 0)
#define MFMA32(a, b, c) __builtin_amdgcn_mfma_f32_32x32x16_bf16((a), (b), (c), 0, 0, 0)

static __device__ __forceinline__ short f2s(float f) {
    __hip_bfloat16 h = __float2bfloat16(f);
    return *reinterpret_cast<short*>(&h);
}
static __device__ __forceinline__ unsigned int cvtpk(float lo, float hi) {
    unsigned int r;
    asm("v_cvt_pk_bf16_f32 %0, %1, %2" : "=v"(r) : "v"(lo), "v"(hi));
    return r;
}
static __device__ __forceinline__ float exp2f_fast(float x) {
#if __has_builtin(__builtin_amdgcn_exp2f)
    return __builtin_amdgcn_exp2f(x);
#else
    return exp2f(x);
#endif
}

// ---------------------------------------------------------------------------
// Kernel 0: pack adj int32 -> uint8  (values 0..4)
// ---------------------------------------------------------------------------
__global__ __launch_bounds__(256)
void adj_pack(const int* __restrict__ adj, unsigned char* __restrict__ out)
{
    const int i = blockIdx.x * 256 + threadIdx.x;   // handles 16 ints
    const int4* src = reinterpret_cast<const int4*>(adj) + i * 4;
    int4 a = src[0], b = src[1], c = src[2], d = src[3];
    uint4 o;
    o.x = (unsigned)a.x | ((unsigned)a.y << 8) | ((unsigned)a.z << 16) | ((unsigned)a.w << 24);
    o.y = (unsigned)b.x | ((unsigned)b.y << 8) | ((unsigned)b.z << 16) | ((unsigned)b.w << 24);
    o.z = (unsigned)c.x | ((unsigned)c.y << 8) | ((unsigned)c.z << 16) | ((unsigned)c.w << 24);
    o.w = (unsigned)d.x | ((unsigned)d.y << 8) | ((unsigned)d.z << 16) | ((unsigned)d.w << 24);
    reinterpret_cast<uint4*>(out)[i] = o;
}

// ---------------------------------------------------------------------------
// Kernel 1: QKV projection (unchanged, verified).
// ---------------------------------------------------------------------------
__global__ __launch_bounds__(256)
void qkv_gemm(const float* __restrict__ x,
              const float* __restrict__ Wq, const float* __restrict__ bq,
              const float* __restrict__ Wk, const float* __restrict__ bk,
              const float* __restrict__ Wv, const float* __restrict__ bv,
              short* __restrict__ Qb, short* __restrict__ Kb, short* __restrict__ Vb)
{
    __shared__ short As[128 * 72];
    __shared__ short Bs[64 * 72];

    const int tid = threadIdx.x;
    const int lane = tid & 63;
    const int wid = tid >> 6;
    const int wr = wid >> 1, wc = wid & 1;
    const int g = lane >> 4, li = lane & 15;

    const int m0 = blockIdx.x * 128;
    const int gc0 = blockIdx.y * 64;
    const int mat = gc0 >> 8;
    const float* W    = (mat == 0) ? Wq : (mat == 1) ? Wk : Wv;
    const float* bias = (mat == 0) ? bq : (mat == 1) ? bk : bv;
    short* Out        = (mat == 0) ? Qb : (mat == 1) ? Kb : Vb;
    const int wc0 = gc0 & 255;

    f32x4 acc[4][2] = {};

    const int sr = tid >> 4;
    const int sc4 = (tid & 15) * 4;

    for (int k0 = 0; k0 < 256; k0 += 64) {
        __syncthreads();
#pragma unroll
        for (int it = 0; it < 8; ++it) {
            int row = sr + it * 16;
            float4 v = *reinterpret_cast<const float4*>(&x[(m0 + row) * 256 + k0 + sc4]);
            short4 s4;
            s4.x = f2s(v.x); s4.y = f2s(v.y); s4.z = f2s(v.z); s4.w = f2s(v.w);
            *reinterpret_cast<short4*>(&As[row * 72 + sc4]) = s4;
        }
#pragma unroll
        for (int it = 0; it < 4; ++it) {
            int row = sr + it * 16;
            float4 v = *reinterpret_cast<const float4*>(&W[(wc0 + row) * 256 + k0 + sc4]);
            short4 s4;
            s4.x = f2s(v.x); s4.y = f2s(v.y); s4.z = f2s(v.z); s4.w = f2s(v.w);
            *reinterpret_cast<short4*>(&Bs[row * 72 + sc4]) = s4;
        }
        __syncthreads();
#pragma unroll
        for (int ks = 0; ks < 2; ++ks) {
            const int kb = ks * 32 + g * 8;
            bf16x8 a[4], bfr[2];
#pragma unroll
            for (int i = 0; i < 4; ++i)
                a[i] = *reinterpret_cast<const bf16x8*>(&As[(wr * 64 + i * 16 + li) * 72 + kb]);
#pragma unroll
            for (int j = 0; j < 2; ++j)
                bfr[j] = *reinterpret_cast<const bf16x8*>(&Bs[(wc * 32 + j * 16 + li) * 72 + kb]);
#pragma unroll
            for (int i = 0; i < 4; ++i)
#pragma unroll
                for (int j = 0; j < 2; ++j)
                    acc[i][j] = MFMA16(a[i], bfr[j], acc[i][j]);
        }
    }

#pragma unroll
    for (int j = 0; j < 2; ++j) {
        const int colW = wc0 + wc * 32 + j * 16 + li;
        const int h = colW >> 5, d = colW & 31;
        const float bv_ = bias[colW];
#pragma unroll
        for (int i = 0; i < 4; ++i) {
#pragma unroll
            for (int r = 0; r < 4; ++r) {
                const int row = m0 + wr * 64 + i * 16 + g * 4 + r;
                const int bb = row >> 10, nq = row & 1023;
                Out[((bb * 8 + h) * 1024 + nq) * 32 + d] = f2s(acc[i][j][r] + bv_);
            }
        }
    }
}

// ---------------------------------------------------------------------------
// Kernel 2: edge-biased flash attention.
// Grid (32, 64), block 256 = 4 waves, 4-way split-k (verified structure).
// Bisect round: KEEP multiplicative bias E[a]=exp(eb[a]) via LDS table and
// the max-pair reduction; REVERT all permlane asm to verified __shfl_xor.
// ---------------------------------------------------------------------------
__global__ __launch_bounds__(256)
void attn3(const short* __restrict__ Qb, const short* __restrict__ Kb,
           const short* __restrict__ Vb, const unsigned char* __restrict__ adj8,
           const float* __restrict__ edge_emb, short* __restrict__ AO)
{
    __shared__ __align__(16) short Vsh[4 * 2304];   // per-wave [32 d][72] V^T
    __shared__ float Etab[8];                       // E[a] = exp(eb[a][h])

    const int tid = threadIdx.x, lane = tid & 63, wid = tid >> 6;
    const int l5 = lane & 31, h32 = lane >> 5;
    const int bh = blockIdx.y, b = bh >> 3, h = bh & 7;
    const int q = blockIdx.x * 32 + l5;

    const short* Qh = Qb + bh * (1024 * 32);
    const short* Kh = Kb + bh * (1024 * 32);
    const short* Vh = Vb + bh * (1024 * 32);
    const unsigned char* adjq = adj8 + (size_t)b * (1024 * 1024) + (size_t)q * 1024;

    if (tid < 5) Etab[tid] = __expf(edge_emb[tid * 8 + h]);
    __syncthreads();

    // Q fragments (B-operand): col=q=l5, k(d) = c*16 + h32*8 + j
    const bf16x8 qf0 = *reinterpret_cast<const bf16x8*>(&Qh[q * 32 + h32 * 8]);
    const bf16x8 qf1 = *reinterpret_cast<const bf16x8*>(&Qh[q * 32 + 16 + h32 * 8]);

    const float c1 = 0.25503486f;   // log2(e)/sqrt(32)
    const f32x16 zero16 = {};

    f32x16 o = {};
    float m2 = -1e30f, l_run = 0.f;

    short* Vt = &Vsh[wid * 2304];
    const int T0 = wid * 4;

    for (int t = 0; t < 4; ++t) {
        const int k0 = (T0 + t) * 64;

        // ---- stage V^T tile (per-wave single buffer) ----
        {
            const int kr = k0 + lane;
            int4 v0 = *reinterpret_cast<const int4*>(&Vh[kr * 32 + 0]);
            int4 v1 = *reinterpret_cast<const int4*>(&Vh[kr * 32 + 8]);
            int4 v2 = *reinterpret_cast<const int4*>(&Vh[kr * 32 + 16]);
            int4 v3 = *reinterpret_cast<const int4*>(&Vh[kr * 32 + 24]);
            const short* s0 = reinterpret_cast<const short*>(&v0);
            const short* s1 = reinterpret_cast<const short*>(&v1);
            const short* s2 = reinterpret_cast<const short*>(&v2);
            const short* s3 = reinterpret_cast<const short*>(&v3);
#pragma unroll
            for (int i = 0; i < 8; ++i) {
                Vt[(i) * 72 + lane]      = s0[i];
                Vt[(8 + i) * 72 + lane]  = s1[i];
                Vt[(16 + i) * 72 + lane] = s2[i];
                Vt[(24 + i) * 72 + lane] = s3[i];
            }
        }

        // ---- adj byte loads (4 codes per u32), issued early ----
        unsigned int a4[8];
#pragma unroll
        for (int ks = 0; ks < 2; ++ks)
#pragma unroll
            for (int rg = 0; rg < 4; ++rg)
                a4[ks * 4 + rg] = *reinterpret_cast<const unsigned int*>(
                    &adjq[k0 + ks * 32 + rg * 8 + h32 * 4]);

        // ---- QK^T swapped: S^T[k][q], k-local = (r&3)+8*(r>>2)+4*h32 ----
        f32x16 s[2];
#pragma unroll
        for (int ks = 0; ks < 2; ++ks) {
            const int krow = k0 + ks * 32 + l5;
            bf16x8 kfa = *reinterpret_cast<const bf16x8*>(&Kh[krow * 32 + h32 * 8]);
            bf16x8 kfb = *reinterpret_cast<const bf16x8*>(&Kh[krow * 32 + 16 + h32 * 8]);
            s[ks] = MFMA32(kfa, qf0, zero16);
            s[ks] = MFMA32(kfb, qf1, s[ks]);
        }

        // ---- tile max over raw scores (pairwise, feeds v_max3) ----
        float tm = s[0][0];
#pragma unroll
        for (int ks = 0; ks < 2; ++ks)
#pragma unroll
            for (int r = ks ? 0 : 1; r < 16; r += 2) {
                const int r1 = (r + 1 < 16) ? r + 1 : r;
                tm = fmaxf(fmaxf(s[ks][r], s[ks][r1]), tm);
            }
        tm = fmaxf(tm, __shfl_xor(tm, 32));   // verified cross-half merge

        const float m2n = fmaxf(m2, tm * c1);
        const float resc = exp2f_fast(m2 - m2n);
        m2 = m2n;
        const float negm2 = -m2;

        // ---- p = exp2(s*c1 - m2) * E[adj]; pack bf16 pairs ----
        unsigned int pw[2][8];
        float lsum = 0.f;
#pragma unroll
        for (int ks = 0; ks < 2; ++ks) {
#pragma unroll
            for (int rg = 0; rg < 4; ++rg) {
                const unsigned int aw4 = a4[ks * 4 + rg] << 2;  // byte offsets
                float pv[4];
#pragma unroll
                for (int j = 0; j < 4; ++j) {
                    const float Ev = *reinterpret_cast<const float*>(
                        reinterpret_cast<const char*>(&Etab[0]) +
                        ((aw4 >> (8 * j)) & 0x3FCu));
                    const float pe = exp2f_fast(fmaf(s[ks][rg * 4 + j], c1, negm2));
                    const float pp = pe * Ev;
                    pv[j] = pp;
                    lsum += pp;
                }
                pw[ks][rg * 2 + 0] = cvtpk(pv[0], pv[1]);
                pw[ks][rg * 2 + 1] = cvtpk(pv[2], pv[3]);
            }
        }
        lsum += __shfl_xor(lsum, 32);         // verified cross-half merge
        l_run = l_run * resc + lsum;

        // ---- rescale O (per-lane uniform) ----
#pragma unroll
        for (int r = 0; r < 16; ++r) o[r] *= resc;

        // ---- PV: O^T += V^T . P^T  (verified shfl_xor exchange) ----
#pragma unroll
        for (int kc = 0; kc < 4; ++kc) {
            const int ks = kc >> 1, half = kc & 1;
            const unsigned int A0 = pw[ks][4 * half + 0], A1 = pw[ks][4 * half + 1];
            const unsigned int B0 = pw[ks][4 * half + 2], B1 = pw[ks][4 * half + 3];
            const unsigned int send0 = h32 ? A0 : B0, send1 = h32 ? A1 : B1;
            const unsigned int rv0 = __shfl_xor(send0, 32);
            const unsigned int rv1 = __shfl_xor(send1, 32);
            const unsigned int own0 = h32 ? B0 : A0, own1 = h32 ? B1 : A1;
            union { unsigned int u[4]; bf16x8 v; } P;
            P.u[0] = h32 ? rv0 : own0;
            P.u[1] = h32 ? rv1 : own1;
            P.u[2] = h32 ? own0 : rv0;
            P.u[3] = h32 ? own1 : rv1;
            bf16x8 vf = *reinterpret_cast<const bf16x8*>(
                &Vt[l5 * 72 + kc * 16 + h32 * 8]);
            o = MFMA32(vf, P.v, o);
        }
    }

    // ---- 4-way split-k flash merge (per-wave own region, 18 f/lane) ----
    float* sc = reinterpret_cast<float*>(Vsh);
    {
        float* myb = sc + wid * 1152 + lane * 18;
        myb[0] = m2;
        myb[1] = l_run;
#pragma unroll
        for (int r = 0; r < 16; ++r) myb[2 + r] = o[r];
    }
    __syncthreads();

    if (wid == 0) {
        float mM = -1e30f;
#pragma unroll
        for (int w = 0; w < 4; ++w) mM = fmaxf(mM, sc[w * 1152 + lane * 18]);
        float lM = 0.f;
        f32x16 ov = {};
#pragma unroll
        for (int w = 0; w < 4; ++w) {
            const float* pb = sc + w * 1152 + lane * 18;
            const float aw = exp2f_fast(pb[0] - mM);
            lM += pb[1] * aw;
#pragma unroll
            for (int r = 0; r < 16; ++r) ov[r] += pb[2 + r] * aw;
        }
        const float inv = 1.0f / lM;
        short* dst = &AO[((size_t)(b * 1024 + q)) * 256 + h * 32];
#pragma unroll
        for (int rg = 0; rg < 4; ++rg) {
            short4 s4;
            s4.x = f2s(ov[rg * 4 + 0] * inv);
            s4.y = f2s(ov[rg * 4 + 1] * inv);
            s4.z = f2s(ov[rg * 4 + 2] * inv);
            s4.w = f2s(ov[rg * 4 + 3] * inv);
            *reinterpret_cast<short4*>(&dst[rg * 8 + h32 * 4]) = s4;
        }
    }
}

// ---------------------------------------------------------------------------
// Kernel 3: output projection (unchanged, verified).
// ---------------------------------------------------------------------------
__global__ __launch_bounds__(256)
void out_gemm(const short* __restrict__ AO, const float* __restrict__ Wo,
              const float* __restrict__ bo, float* __restrict__ out)
{
    __shared__ short As[128 * 72];
    __shared__ short Bs[64 * 72];

    const int tid = threadIdx.x, lane = tid & 63, wid = tid >> 6;
    const int wr = wid >> 1, wcn = wid & 1;
    const int g = lane >> 4, li = lane & 15;
    const int m0 = blockIdx.x * 128, n0 = blockIdx.y * 64;

    f32x4 acc[4][2] = {};
    const int ar = tid >> 3, ac8 = (tid & 7) * 8;
    const int br = tid >> 4, bc4 = (tid & 15) * 4;

    for (int k0 = 0; k0 < 256; k0 += 64) {
        __syncthreads();
#pragma unroll
        for (int it = 0; it < 4; ++it) {
            int row = ar + it * 32;
            *reinterpret_cast<int4*>(&As[row * 72 + ac8]) =
                *reinterpret_cast<const int4*>(&AO[(m0 + row) * 256 + k0 + ac8]);
        }
#pragma unroll
        for (int it = 0; it < 4; ++it) {
            int row = br + it * 16;
            float4 v = *reinterpret_cast<const float4*>(&Wo[(n0 + row) * 256 + k0 + bc4]);
            short4 s4; s4.x = f2s(v.x); s4.y = f2s(v.y); s4.z = f2s(v.z); s4.w = f2s(v.w);
            *reinterpret_cast<short4*>(&Bs[row * 72 + bc4]) = s4;
        }
        __syncthreads();
#pragma unroll
        for (int ks = 0; ks < 2; ++ks) {
            const int kb = ks * 32 + g * 8;
            bf16x8 a[4], bb[2];
#pragma unroll
            for (int i = 0; i < 4; ++i)
                a[i] = *reinterpret_cast<const bf16x8*>(&As[(wr * 64 + i * 16 + li) * 72 + kb]);
#pragma unroll
            for (int j = 0; j < 2; ++j)
                bb[j] = *reinterpret_cast<const bf16x8*>(&Bs[(wcn * 32 + j * 16 + li) * 72 + kb]);
#pragma unroll
            for (int i = 0; i < 4; ++i)
#pragma unroll
                for (int j = 0; j < 2; ++j)
                    acc[i][j] = MFMA16(a[i], bb[j], acc[i][j]);
        }
    }
#pragma unroll
    for (int j = 0; j < 2; ++j) {
        const int col = n0 + wcn * 32 + j * 16 + li;
        const float bv_ = bo[col];
#pragma unroll
        for (int i = 0; i < 4; ++i)
#pragma unroll
            for (int r = 0; r < 4; ++r) {
                const int row = m0 + wr * 64 + i * 16 + g * 4 + r;
                out[row * 256 + col] = acc[i][j][r] + bv_;
            }
    }
}

extern "C" void kernel_launch(void* const* d_in, const int* in_sizes, int n_in,
                              void* d_out, int out_size, void* d_ws, size_t ws_size,
                              hipStream_t stream)
{
    const float* x  = (const float*)d_in[0];
    const int*   adj = (const int*)d_in[1];
    const float* Wq = (const float*)d_in[2];
    const float* bq = (const float*)d_in[3];
    const float* Wk = (const float*)d_in[4];
    const float* bk = (const float*)d_in[5];
    const float* Wv = (const float*)d_in[6];
    const float* bv = (const float*)d_in[7];
    const float* Wo = (const float*)d_in[8];
    const float* bo = (const float*)d_in[9];
    const float* ee = (const float*)d_in[10];
    float* out = (float*)d_out;

    // Workspace: Qb/Kb/Vb [64][1024][32] bf16 (4MB each), AO [8192][256] bf16 (4MB),
    // adj8 [8][1024][1024] u8 (8MB)  -> 24MB total (known-good budget)
    short* Qb = (short*)d_ws;
    short* Kb = Qb + 2 * 1024 * 1024;
    short* Vb = Kb + 2 * 1024 * 1024;
    short* AO = Vb + 2 * 1024 * 1024;
    unsigned char* adj8 = (unsigned char*)(AO + 2 * 1024 * 1024);

    adj_pack<<<2048, 256, 0, stream>>>(adj, adj8);
    qkv_gemm<<<dim3(64, 12), 256, 0, stream>>>(x, Wq, bq, Wk, bk, Wv, bv, Qb, Kb, Vb);
    attn3<<<dim3(32, 64), 256, 0, stream>>>(Qb, Kb, Vb, adj8, ee, AO);
    out_gemm<<<dim3(64, 4), 256, 0, stream>>>(AO, Wo, bo, out);
}

// Round 8
// 65.500 us; speedup vs baseline: 1.3463x; 1.3451x over previous
//
#include <hip/hip_runtime.h>
#include <hip/hip_bf16.h>

typedef float f32x4 __attribute__((ext_vector_type(4)));
typedef float f32x16 __attribute__((ext_vector_type(16)));
typedef __bf16 bf16x8 __attribute__((ext_vector_type(8)));

#define MFMA16(a, b, c) __builtin_amdgcn_mfma_f32_16x16x32_bf16((a), (b), (c), 0, 0, 0)
#define MFMA32(a, b, c) __builtin_amdgcn_mfma_f32_32x32x16_bf16((a), (b), (c), 0, 0, 0)

static __device__ __forceinline__ short f2s(float f) {
    __hip_bfloat16 h = __float2bfloat16(f);
    return *reinterpret_cast<short*>(&h);
}
static __device__ __forceinline__ unsigned int cvtpk(float lo, float hi) {
    unsigned int r;
    asm("v_cvt_pk_bf16_f32 %0, %1, %2" : "=v"(r) : "v"(lo), "v"(hi));
    return r;
}
static __device__ __forceinline__ float exp2f_fast(float x) {
#if __has_builtin(__builtin_amdgcn_exp2f)
    return __builtin_amdgcn_exp2f(x);
#else
    return exp2f(x);
#endif
}

// ---------------------------------------------------------------------------
// Kernel 0: gather adj int32 -> u8 codes in wave order:
//   adjG[((b*32+qt)*16 + kt)*512 + i*64 + lane]  (u32 = 4 codes)
//   holds codes (q = qt*32 + (lane&31), k = kt*64 + (i>>2)*32 + (i&3)*8 +
//   (lane>>5)*4 + {0..3})  -> attn reads are fully coalesced.
// ---------------------------------------------------------------------------
__global__ __launch_bounds__(256)
void adj_gather(const int* __restrict__ adj, unsigned int* __restrict__ adjG)
{
    const int tid = threadIdx.x;
    const int lane = tid & 63;
    const int i = (blockIdx.x & 1) * 4 + (tid >> 6);
    const int kt = blockIdx.x >> 1;
    const int qt = blockIdx.y;
    const int b  = blockIdx.z;

    const int q = qt * 32 + (lane & 31);
    const int k = kt * 64 + (i >> 2) * 32 + (i & 3) * 8 + (lane >> 5) * 4;
    const int4 c = *reinterpret_cast<const int4*>(
        &adj[((size_t)(b * 1024 + q)) * 1024 + k]);
    const unsigned int packed =
        (unsigned)c.x | ((unsigned)c.y << 8) | ((unsigned)c.z << 16) | ((unsigned)c.w << 24);
    adjG[(((size_t)(b * 32 + qt)) * 16 + kt) * 512 + i * 64 + lane] = packed;
}

// ---------------------------------------------------------------------------
// Kernel 1: QKV projection (unchanged, verified).
// ---------------------------------------------------------------------------
__global__ __launch_bounds__(256)
void qkv_gemm(const float* __restrict__ x,
              const float* __restrict__ Wq, const float* __restrict__ bq,
              const float* __restrict__ Wk, const float* __restrict__ bk,
              const float* __restrict__ Wv, const float* __restrict__ bv,
              short* __restrict__ Qb, short* __restrict__ Kb, short* __restrict__ Vb)
{
    __shared__ short As[128 * 72];
    __shared__ short Bs[64 * 72];

    const int tid = threadIdx.x;
    const int lane = tid & 63;
    const int wid = tid >> 6;
    const int wr = wid >> 1, wc = wid & 1;
    const int g = lane >> 4, li = lane & 15;

    const int m0 = blockIdx.x * 128;
    const int gc0 = blockIdx.y * 64;
    const int mat = gc0 >> 8;
    const float* W    = (mat == 0) ? Wq : (mat == 1) ? Wk : Wv;
    const float* bias = (mat == 0) ? bq : (mat == 1) ? bk : bv;
    short* Out        = (mat == 0) ? Qb : (mat == 1) ? Kb : Vb;
    const int wc0 = gc0 & 255;

    f32x4 acc[4][2] = {};

    const int sr = tid >> 4;
    const int sc4 = (tid & 15) * 4;

    for (int k0 = 0; k0 < 256; k0 += 64) {
        __syncthreads();
#pragma unroll
        for (int it = 0; it < 8; ++it) {
            int row = sr + it * 16;
            float4 v = *reinterpret_cast<const float4*>(&x[(m0 + row) * 256 + k0 + sc4]);
            short4 s4;
            s4.x = f2s(v.x); s4.y = f2s(v.y); s4.z = f2s(v.z); s4.w = f2s(v.w);
            *reinterpret_cast<short4*>(&As[row * 72 + sc4]) = s4;
        }
#pragma unroll
        for (int it = 0; it < 4; ++it) {
            int row = sr + it * 16;
            float4 v = *reinterpret_cast<const float4*>(&W[(wc0 + row) * 256 + k0 + sc4]);
            short4 s4;
            s4.x = f2s(v.x); s4.y = f2s(v.y); s4.z = f2s(v.z); s4.w = f2s(v.w);
            *reinterpret_cast<short4*>(&Bs[row * 72 + sc4]) = s4;
        }
        __syncthreads();
#pragma unroll
        for (int ks = 0; ks < 2; ++ks) {
            const int kb = ks * 32 + g * 8;
            bf16x8 a[4], bfr[2];
#pragma unroll
            for (int i = 0; i < 4; ++i)
                a[i] = *reinterpret_cast<const bf16x8*>(&As[(wr * 64 + i * 16 + li) * 72 + kb]);
#pragma unroll
            for (int j = 0; j < 2; ++j)
                bfr[j] = *reinterpret_cast<const bf16x8*>(&Bs[(wc * 32 + j * 16 + li) * 72 + kb]);
#pragma unroll
            for (int i = 0; i < 4; ++i)
#pragma unroll
                for (int j = 0; j < 2; ++j)
                    acc[i][j] = MFMA16(a[i], bfr[j], acc[i][j]);
        }
    }

#pragma unroll
    for (int j = 0; j < 2; ++j) {
        const int colW = wc0 + wc * 32 + j * 16 + li;
        const int h = colW >> 5, d = colW & 31;
        const float bv_ = bias[colW];
#pragma unroll
        for (int i = 0; i < 4; ++i) {
#pragma unroll
            for (int r = 0; r < 4; ++r) {
                const int row = m0 + wr * 64 + i * 16 + g * 4 + r;
                const int bb = row >> 10, nq = row & 1023;
                Out[((bb * 8 + h) * 1024 + nq) * 32 + d] = f2s(acc[i][j][r] + bv_);
            }
        }
    }
}

// ---------------------------------------------------------------------------
// Kernel 2: edge-biased flash attention, shared-staging structure.
// Grid (8, 64) swizzled; block 256 = 4 waves; wave w owns q-tile qb*4+w.
// All waves iterate the SAME 16 k-tiles; K and V^T staged cooperatively
// (coalesced 1KB/wave loads) into double-buffered LDS, shared by all waves.
// One barrier per tile; next-tile loads issue before compute (vmcnt hides).
// Softmax/PV/epilogue identical to verified round-7 code.
// ---------------------------------------------------------------------------
__global__ __launch_bounds__(256)
void attn4(const short* __restrict__ Qb, const short* __restrict__ Kb,
           const short* __restrict__ Vb, const unsigned int* __restrict__ adjG,
           const float* __restrict__ edge_emb, short* __restrict__ AO)
{
    __shared__ __align__(16) short Ks[2][64 * 36];   // [row][d] padded (72B rows)
    __shared__ __align__(16) short Vt[2][32 * 72];   // [d][row] (144B rows)
    __shared__ float Etab[8];

    const int tid = threadIdx.x, lane = tid & 63, wid = tid >> 6;
    const int l5 = lane & 31, h32 = lane >> 5;

    // bijective chunked XCD swizzle (512 blocks = 8 XCD x 64)
    const int orig = blockIdx.x + blockIdx.y * 8;
    const int flat = (orig & 7) * 64 + (orig >> 3);
    const int qb = flat & 7, bh = flat >> 3;
    const int b = bh >> 3, h = bh & 7;
    const int qt = qb * 4 + wid;         // wave's q-tile (0..31)
    const int q  = qt * 32 + l5;

    const short* Qh = Qb + bh * (1024 * 32);
    const short* Kh = Kb + bh * (1024 * 32);
    const short* Vh = Vb + bh * (1024 * 32);
    const unsigned int* adjT = adjG + ((size_t)(b * 32 + qt)) * 16 * 512;

    if (tid < 5) Etab[tid] = __expf(edge_emb[tid * 8 + h]);

    // Q fragments (B-operand): col=q=l5, k(d) = c*16 + h32*8 + j
    const bf16x8 qf0 = *reinterpret_cast<const bf16x8*>(&Qh[q * 32 + h32 * 8]);
    const bf16x8 qf1 = *reinterpret_cast<const bf16x8*>(&Qh[q * 32 + 16 + h32 * 8]);

    const float c1 = 0.25503486f;   // log2(e)/sqrt(32)
    const f32x16 zero16 = {};

    f32x16 o = {};
    float m2 = -1e30f, l_run = 0.f;

    // staging map: thread -> (row sr = tid>>2, 16B chunk sc = (tid&3)*8 shorts)
    const int sr = tid >> 2;
    const int sc = (tid & 3) * 8;

    // prologue: load + write tile 0 into buffer 0
    {
        int4 kr = *reinterpret_cast<const int4*>(&Kh[sr * 32 + sc]);
        int4 vr = *reinterpret_cast<const int4*>(&Vh[sr * 32 + sc]);
        *reinterpret_cast<short4*>(&Ks[0][sr * 36 + sc])     = *reinterpret_cast<short4*>(&kr);
        *reinterpret_cast<short4*>(&Ks[0][sr * 36 + sc + 4]) = *(reinterpret_cast<short4*>(&kr) + 1);
        const short* vs = reinterpret_cast<const short*>(&vr);
#pragma unroll
        for (int i = 0; i < 8; ++i) Vt[0][(sc + i) * 72 + sr] = vs[i];
    }
    __syncthreads();

    for (int t = 0; t < 16; ++t) {
        const int cur = t & 1;
        const int k0 = t * 64;

        // ---- issue next-tile global loads (hidden under compute) ----
        int4 kn, vn;
        if (t < 15) {
            kn = *reinterpret_cast<const int4*>(&Kh[(k0 + 64 + sr) * 32 + sc]);
            vn = *reinterpret_cast<const int4*>(&Vh[(k0 + 64 + sr) * 32 + sc]);
        }

        // ---- adj loads (coalesced gathered layout) ----
        unsigned int a4[8];
#pragma unroll
        for (int i = 0; i < 8; ++i)
            a4[i] = adjT[t * 512 + i * 64 + lane];

        // ---- QK^T from LDS K frags: S^T[k][q] ----
        f32x16 s[2];
#pragma unroll
        for (int ks = 0; ks < 2; ++ks) {
            union { short4 h4[2]; bf16x8 v; } kfa, kfb;
            const int rowb = (ks * 32 + l5) * 36;
            kfa.h4[0] = *reinterpret_cast<const short4*>(&Ks[cur][rowb + h32 * 8]);
            kfa.h4[1] = *reinterpret_cast<const short4*>(&Ks[cur][rowb + h32 * 8 + 4]);
            kfb.h4[0] = *reinterpret_cast<const short4*>(&Ks[cur][rowb + 16 + h32 * 8]);
            kfb.h4[1] = *reinterpret_cast<const short4*>(&Ks[cur][rowb + 16 + h32 * 8 + 4]);
            s[ks] = MFMA32(kfa.v, qf0, zero16);
            s[ks] = MFMA32(kfb.v, qf1, s[ks]);
        }

        // ---- tile max over raw scores ----
        float tm = s[0][0];
#pragma unroll
        for (int ks = 0; ks < 2; ++ks)
#pragma unroll
            for (int r = ks ? 0 : 1; r < 16; r += 2) {
                const int r1 = (r + 1 < 16) ? r + 1 : r;
                tm = fmaxf(fmaxf(s[ks][r], s[ks][r1]), tm);
            }
        tm = fmaxf(tm, __shfl_xor(tm, 32));

        const float m2n = fmaxf(m2, tm * c1);
        const float resc = exp2f_fast(m2 - m2n);
        m2 = m2n;
        const float negm2 = -m2;

        // ---- p = exp2(s*c1 - m2) * E[adj]; pack bf16 pairs ----
        unsigned int pw[2][8];
        float lsum = 0.f;
#pragma unroll
        for (int ks = 0; ks < 2; ++ks) {
#pragma unroll
            for (int rg = 0; rg < 4; ++rg) {
                const unsigned int aw4 = a4[ks * 4 + rg] << 2;
                float pv[4];
#pragma unroll
                for (int j = 0; j < 4; ++j) {
                    const float Ev = *reinterpret_cast<const float*>(
                        reinterpret_cast<const char*>(&Etab[0]) +
                        ((aw4 >> (8 * j)) & 0x3FCu));
                    const float pe = exp2f_fast(fmaf(s[ks][rg * 4 + j], c1, negm2));
                    const float pp = pe * Ev;
                    pv[j] = pp;
                    lsum += pp;
                }
                pw[ks][rg * 2 + 0] = cvtpk(pv[0], pv[1]);
                pw[ks][rg * 2 + 1] = cvtpk(pv[2], pv[3]);
            }
        }
        lsum += __shfl_xor(lsum, 32);
        l_run = l_run * resc + lsum;

#pragma unroll
        for (int r = 0; r < 16; ++r) o[r] *= resc;

        // ---- PV: O^T += V^T . P^T  (verified shfl exchange) ----
#pragma unroll
        for (int kc = 0; kc < 4; ++kc) {
            const int ks = kc >> 1, half = kc & 1;
            const unsigned int A0 = pw[ks][4 * half + 0], A1 = pw[ks][4 * half + 1];
            const unsigned int B0 = pw[ks][4 * half + 2], B1 = pw[ks][4 * half + 3];
            const unsigned int send0 = h32 ? A0 : B0, send1 = h32 ? A1 : B1;
            const unsigned int rv0 = __shfl_xor(send0, 32);
            const unsigned int rv1 = __shfl_xor(send1, 32);
            const unsigned int own0 = h32 ? B0 : A0, own1 = h32 ? B1 : A1;
            union { unsigned int u[4]; bf16x8 v; } P;
            P.u[0] = h32 ? rv0 : own0;
            P.u[1] = h32 ? rv1 : own1;
            P.u[2] = h32 ? own0 : rv0;
            P.u[3] = h32 ? own1 : rv1;
            bf16x8 vf = *reinterpret_cast<const bf16x8*>(
                &Vt[cur][l5 * 72 + kc * 16 + h32 * 8]);
            o = MFMA32(vf, P.v, o);
        }

        // ---- write next tile into other buffer; single barrier per iter ----
        if (t < 15) {
            *reinterpret_cast<short4*>(&Ks[cur ^ 1][sr * 36 + sc])     = *reinterpret_cast<short4*>(&kn);
            *reinterpret_cast<short4*>(&Ks[cur ^ 1][sr * 36 + sc + 4]) = *(reinterpret_cast<short4*>(&kn) + 1);
            const short* vs = reinterpret_cast<const short*>(&vn);
#pragma unroll
            for (int i = 0; i < 8; ++i) Vt[cur ^ 1][(sc + i) * 72 + sr] = vs[i];
            __syncthreads();
        }
    }

    // ---- epilogue: every wave writes its own q-tile (no merge needed) ----
    const float inv = 1.0f / l_run;
    short* dst = &AO[((size_t)(b * 1024 + q)) * 256 + h * 32];
#pragma unroll
    for (int rg = 0; rg < 4; ++rg) {
        short4 s4;
        s4.x = f2s(o[rg * 4 + 0] * inv);
        s4.y = f2s(o[rg * 4 + 1] * inv);
        s4.z = f2s(o[rg * 4 + 2] * inv);
        s4.w = f2s(o[rg * 4 + 3] * inv);
        *reinterpret_cast<short4*>(&dst[rg * 8 + h32 * 4]) = s4;
    }
}

// ---------------------------------------------------------------------------
// Kernel 3: output projection (unchanged, verified).
// ---------------------------------------------------------------------------
__global__ __launch_bounds__(256)
void out_gemm(const short* __restrict__ AO, const float* __restrict__ Wo,
              const float* __restrict__ bo, float* __restrict__ out)
{
    __shared__ short As[128 * 72];
    __shared__ short Bs[64 * 72];

    const int tid = threadIdx.x, lane = tid & 63, wid = tid >> 6;
    const int wr = wid >> 1, wcn = wid & 1;
    const int g = lane >> 4, li = lane & 15;
    const int m0 = blockIdx.x * 128, n0 = blockIdx.y * 64;

    f32x4 acc[4][2] = {};
    const int ar = tid >> 3, ac8 = (tid & 7) * 8;
    const int br = tid >> 4, bc4 = (tid & 15) * 4;

    for (int k0 = 0; k0 < 256; k0 += 64) {
        __syncthreads();
#pragma unroll
        for (int it = 0; it < 4; ++it) {
            int row = ar + it * 32;
            *reinterpret_cast<int4*>(&As[row * 72 + ac8]) =
                *reinterpret_cast<const int4*>(&AO[(m0 + row) * 256 + k0 + ac8]);
        }
#pragma unroll
        for (int it = 0; it < 4; ++it) {
            int row = br + it * 16;
            float4 v = *reinterpret_cast<const float4*>(&Wo[(n0 + row) * 256 + k0 + bc4]);
            short4 s4; s4.x = f2s(v.x); s4.y = f2s(v.y); s4.z = f2s(v.z); s4.w = f2s(v.w);
            *reinterpret_cast<short4*>(&Bs[row * 72 + bc4]) = s4;
        }
        __syncthreads();
#pragma unroll
        for (int ks = 0; ks < 2; ++ks) {
            const int kb = ks * 32 + g * 8;
            bf16x8 a[4], bb[2];
#pragma unroll
            for (int i = 0; i < 4; ++i)
                a[i] = *reinterpret_cast<const bf16x8*>(&As[(wr * 64 + i * 16 + li) * 72 + kb]);
#pragma unroll
            for (int j = 0; j < 2; ++j)
                bb[j] = *reinterpret_cast<const bf16x8*>(&Bs[(wcn * 32 + j * 16 + li) * 72 + kb]);
#pragma unroll
            for (int i = 0; i < 4; ++i)
#pragma unroll
                for (int j = 0; j < 2; ++j)
                    acc[i][j] = MFMA16(a[i], bb[j], acc[i][j]);
        }
    }
#pragma unroll
    for (int j = 0; j < 2; ++j) {
        const int col = n0 + wcn * 32 + j * 16 + li;
        const float bv_ = bo[col];
#pragma unroll
        for (int i = 0; i < 4; ++i)
#pragma unroll
            for (int r = 0; r < 4; ++r) {
                const int row = m0 + wr * 64 + i * 16 + g * 4 + r;
                out[row * 256 + col] = acc[i][j][r] + bv_;
            }
    }
}

extern "C" void kernel_launch(void* const* d_in, const int* in_sizes, int n_in,
                              void* d_out, int out_size, void* d_ws, size_t ws_size,
                              hipStream_t stream)
{
    const float* x  = (const float*)d_in[0];
    const int*   adj = (const int*)d_in[1];
    const float* Wq = (const float*)d_in[2];
    const float* bq = (const float*)d_in[3];
    const float* Wk = (const float*)d_in[4];
    const float* bk = (const float*)d_in[5];
    const float* Wv = (const float*)d_in[6];
    const float* bv = (const float*)d_in[7];
    const float* Wo = (const float*)d_in[8];
    const float* bo = (const float*)d_in[9];
    const float* ee = (const float*)d_in[10];
    float* out = (float*)d_out;

    // Workspace: Qb/Kb/Vb [64][1024][32] bf16 (4MB each), AO [8192][256] bf16 (4MB),
    // adjG [8][32][16][8][64] u32 (8MB)  -> 24MB total (known-good budget)
    short* Qb = (short*)d_ws;
    short* Kb = Qb + 2 * 1024 * 1024;
    short* Vb = Kb + 2 * 1024 * 1024;
    short* AO = Vb + 2 * 1024 * 1024;
    unsigned int* adjG = (unsigned int*)(AO + 2 * 1024 * 1024);

    adj_gather<<<dim3(32, 32, 8), 256, 0, stream>>>(adj, adjG);
    qkv_gemm<<<dim3(64, 12), 256, 0, stream>>>(x, Wq, bq, Wk, bk, Wv, bv, Qb, Kb, Vb);
    attn4<<<dim3(8, 64), 256, 0, stream>>>(Qb, Kb, Vb, adjG, ee, AO);
    out_gemm<<<dim3(64, 4), 256, 0, stream>>>(AO, Wo, bo, out);
}